// Round 3
// baseline (103.786 us; speedup 1.0000x reference)
//
#include <hip/hip_runtime.h>

#define VOCAB 100000
#define DIM 128
#define BATCH 65536
#define NEG 5

#define NBKT 3125          // ceil(VOCAB / 32): 32 rows per bucket
#define CAPA 32            // input-ref bucket capacity (mean ~21)
#define CAPC 32            // ctx-ref bucket capacity (mean ~21)
#define CAPN 128           // neg-ref bucket capacity (mean ~105)
#define OVF  4096          // overflow list capacity per class

#define NGA  (NBKT*CAPA + OVF)            // 104096 phaseA groups
#define NGC  (NBKT*CAPC)                  // 100000
#define NGN  (NBKT*CAPN)                  // 400000
#define NGBC (NGC + NGN + OVF + OVF)      // 508192 phaseBC groups
#define NPART (NGBC/16)                   // 31762 block partials

#define NCUR (3*NBKT + 3)

__device__ __forceinline__ float log_sigmoid(float x) {
    return fminf(x, 0.0f) - log1pf(expf(-fabsf(x)));
}
__device__ __forceinline__ float dot4(float4 a, float4 b) {
    return a.x * b.x + a.y * b.y + a.z * b.z + a.w * b.w;
}
__device__ __forceinline__ unsigned bf16rne(float f) {
    unsigned u = __float_as_uint(f);
    return (u + 0x7fffu + ((u >> 16) & 1u)) >> 16;
}
__device__ __forceinline__ unsigned pack2(float a, float b) {
    return bf16rne(a) | (bf16rne(b) << 16);
}
__device__ __forceinline__ float lo16(unsigned u) { return __uint_as_float(u << 16); }
__device__ __forceinline__ float hi16(unsigned u) { return __uint_as_float(u & 0xffff0000u); }

// bijective XCD-chunk swizzle (m204 form): physical bid -> logical bid so each
// XCD gets a contiguous chunk of logical work (same-bucket blocks share an L2)
__device__ __forceinline__ int xcd_swz(int bid, int nblk) {
    int q = nblk >> 3, r = nblk & 7;
    int xcd = bid & 7, idx = bid >> 3;
    return (xcd < r ? xcd * (q + 1) : r * (q + 1) + (xcd - r) * q) + idx;
}

// ---- workspace layout (bytes) ----
#define E_OFF     0                        // ushort[BATCH*DIM] = 16,777,216
#define BKTA_OFF  16777216                 // uint2[NBKT*CAPA]  =    800,000
#define BKTC_OFF  17577216                 // uint2[NBKT*CAPC]  =    800,000
#define BKTN_OFF  18377216                 // uint2[NBKT*CAPN]  =  3,200,000
#define OVFA_OFF  21577216                 // uint2[OVF] = 32,768
#define OVFC_OFF  21609984
#define OVFN_OFF  21642752
#define CUR_OFF   21675520                 // int[NCUR] = 37,512 (pad 37,632)
#define PART_OFF  21713152                 // float[NPART]

__global__ __launch_bounds__(256) void k_zero(int* __restrict__ cur) {
    int i = blockIdx.x * 256 + threadIdx.x;
    if (i < NCUR) cur[i] = 0;
}

__global__ __launch_bounds__(256) void k_scatter(
    const int* __restrict__ iw, const int* __restrict__ cw,
    const int* __restrict__ negf,
    uint2* __restrict__ bktA, uint2* __restrict__ bktC, uint2* __restrict__ bktN,
    uint2* __restrict__ ovfA, uint2* __restrict__ ovfC, uint2* __restrict__ ovfN,
    int* __restrict__ cur)
{
    int i = blockIdx.x * 256 + threadIdx.x;   // [0, 458752)
    int key, b, which;
    if (i < BATCH)            { which = 0; b = i;             key = iw[b]; }
    else if (i < 2 * BATCH)   { which = 1; b = i - BATCH;     key = cw[b]; }
    else { int j = i - 2 * BATCH; which = 2; b = j / NEG;     key = negf[j]; }

    int bkt = key >> 5;
    uint2 ref = make_uint2((unsigned)key, (unsigned)b);
    if (which == 0) {
        int p = atomicAdd(&cur[bkt], 1);
        if (p < CAPA) bktA[bkt * CAPA + p] = ref;
        else { int q = atomicAdd(&cur[3 * NBKT + 0], 1); if (q < OVF) ovfA[q] = ref; }
    } else if (which == 1) {
        int p = atomicAdd(&cur[NBKT + bkt], 1);
        if (p < CAPC) bktC[bkt * CAPC + p] = ref;
        else { int q = atomicAdd(&cur[3 * NBKT + 1], 1); if (q < OVF) ovfC[q] = ref; }
    } else {
        int p = atomicAdd(&cur[2 * NBKT + bkt], 1);
        if (p < CAPN) bktN[bkt * CAPN + p] = ref;
        else { int q = atomicAdd(&cur[3 * NBKT + 2], 1); if (q < OVF) ovfN[q] = ref; }
    }
}

// Phase A: input-refs in ascending-row order; gather W_in row, store bf16 to E
// E layout matches the lane pattern: lane l holds floats {4l..4l+3, 64+4l..64+4l+3}
__global__ __launch_bounds__(256) void k_phaseA(
    const float* __restrict__ W_in, const uint2* __restrict__ bktA,
    const uint2* __restrict__ ovfA, const int* __restrict__ cur,
    ushort* __restrict__ E)
{
    const int lane16 = threadIdx.x & 15;
    const int grp = threadIdx.x >> 4;
    const int lbid = xcd_swz(blockIdx.x, NGA / 16);
    const int g = lbid * 16 + grp;

    bool valid = false;
    uint2 ref;
    if (g < NBKT * CAPA) {
        int bkt = g >> 5, slot = g & 31;
        int cnt = min(cur[bkt], CAPA);
        if (slot < cnt) { valid = true; ref = bktA[g]; }
    } else {
        int j = g - NBKT * CAPA;
        if (j < min(cur[3 * NBKT + 0], OVF)) { valid = true; ref = ovfA[j]; }
    }
    if (!valid) return;

    const float4* __restrict__ W4 = (const float4*)W_in;
    const int r = (int)ref.x;
    const float4 f0 = W4[r * 32 + lane16];
    const float4 f1 = W4[r * 32 + 16 + lane16];

    uint4 v;
    v.x = pack2(f0.x, f0.y);
    v.y = pack2(f0.z, f0.w);
    v.z = pack2(f1.x, f1.y);
    v.w = pack2(f1.z, f1.w);
    *(uint4*)(((char*)E) + (size_t)ref.y * 256 + lane16 * 16) = v;
}

// Phase BC: ctx-refs (ls(+dot) vs W_ctx) then neg-refs (ls(-dot) vs W_in),
// both in ascending-row order; E read back from L3-resident scratch.
__global__ __launch_bounds__(256) void k_phaseBC(
    const float* __restrict__ W_in, const float* __restrict__ W_ctx,
    const uint2* __restrict__ bktC, const uint2* __restrict__ bktN,
    const uint2* __restrict__ ovfC, const uint2* __restrict__ ovfN,
    const int* __restrict__ cur, const ushort* __restrict__ E,
    float* __restrict__ partials)
{
    const int lane16 = threadIdx.x & 15;
    const int grp = threadIdx.x >> 4;
    const int lbid = xcd_swz(blockIdx.x, NGBC / 16);
    const int g = lbid * 16 + grp;

    bool valid = false;
    float sign = 1.0f;
    const float* tbl = W_ctx;
    uint2 ref;
    if (g < NGC) {
        int bkt = g >> 5, slot = g & 31;
        int cnt = min(cur[NBKT + bkt], CAPC);
        if (slot < cnt) { valid = true; ref = bktC[g]; }
    } else if (g < NGC + NGN) {
        int q = g - NGC;
        int bkt = q >> 7, slot = q & 127;
        int cnt = min(cur[2 * NBKT + bkt], CAPN);
        if (slot < cnt) { valid = true; ref = bktN[q]; }
        tbl = W_in; sign = -1.0f;
    } else if (g < NGC + NGN + OVF) {
        int j = g - (NGC + NGN);
        if (j < min(cur[3 * NBKT + 1], OVF)) { valid = true; ref = ovfC[j]; }
    } else {
        int j = g - (NGC + NGN + OVF);
        if (j < min(cur[3 * NBKT + 2], OVF)) { valid = true; ref = ovfN[j]; }
        tbl = W_in; sign = -1.0f;
    }

    float loss = 0.0f;
    if (valid) {
        const float4* __restrict__ T4 = (const float4*)tbl;
        const int r = (int)ref.x;
        const float4 t0 = T4[r * 32 + lane16];
        const float4 t1 = T4[r * 32 + 16 + lane16];
        const uint4 ev = *(const uint4*)(((const char*)E) + (size_t)ref.y * 256 + lane16 * 16);

        float4 e0 = make_float4(lo16(ev.x), hi16(ev.x), lo16(ev.y), hi16(ev.y));
        float4 e1 = make_float4(lo16(ev.z), hi16(ev.z), lo16(ev.w), hi16(ev.w));
        float d = dot4(t0, e0) + dot4(t1, e1);

        #pragma unroll
        for (int m = 1; m <= 8; m <<= 1) d += __shfl_xor(d, m);

        if (lane16 == 0) loss = log_sigmoid(sign * d);
    }

    __shared__ float s[16];
    if (lane16 == 0) s[grp] = loss;
    __syncthreads();
    if (threadIdx.x == 0) {
        float t = 0.0f;
        #pragma unroll
        for (int i = 0; i < 16; ++i) t += s[i];
        partials[lbid] = t;
    }
}

__global__ __launch_bounds__(1024) void k_final(
    const float* __restrict__ partials, float* __restrict__ out)
{
    __shared__ float s[1024];
    float t = 0.0f;
    for (int i = threadIdx.x; i < NPART; i += 1024) t += partials[i];
    s[threadIdx.x] = t;
    __syncthreads();
    for (int w = 512; w > 0; w >>= 1) {
        if (threadIdx.x < w) s[threadIdx.x] += s[threadIdx.x + w];
        __syncthreads();
    }
    if (threadIdx.x == 0) out[0] = -s[0] / (float)BATCH;
}

extern "C" void kernel_launch(void* const* d_in, const int* in_sizes, int n_in,
                              void* d_out, int out_size, void* d_ws, size_t ws_size,
                              hipStream_t stream) {
    const float* W_in   = (const float*)d_in[0];
    const float* W_ctx  = (const float*)d_in[1];
    const int*   iw     = (const int*)d_in[2];
    const int*   cw     = (const int*)d_in[3];
    const int*   negf   = (const int*)d_in[4];

    char* w = (char*)d_ws;
    ushort* E      = (ushort*)(w + E_OFF);
    uint2*  bktA   = (uint2*)(w + BKTA_OFF);
    uint2*  bktC   = (uint2*)(w + BKTC_OFF);
    uint2*  bktN   = (uint2*)(w + BKTN_OFF);
    uint2*  ovfA   = (uint2*)(w + OVFA_OFF);
    uint2*  ovfC   = (uint2*)(w + OVFC_OFF);
    uint2*  ovfN   = (uint2*)(w + OVFN_OFF);
    int*    cur    = (int*)(w + CUR_OFF);
    float*  parts  = (float*)(w + PART_OFF);
    float*  out    = (float*)d_out;

    k_zero<<<(NCUR + 255) / 256, 256, 0, stream>>>(cur);
    k_scatter<<<(7 * BATCH) / 256, 256, 0, stream>>>(iw, cw, negf,
                bktA, bktC, bktN, ovfA, ovfC, ovfN, cur);
    k_phaseA<<<NGA / 16, 256, 0, stream>>>(W_in, bktA, ovfA, cur, E);
    k_phaseBC<<<NGBC / 16, 256, 0, stream>>>(W_in, W_ctx, bktC, bktN,
                ovfC, ovfN, cur, E, parts);
    k_final<<<1, 1024, 0, stream>>>(parts, out);
}

// Round 4
// 47.825 us; speedup vs baseline: 2.1701x; 2.1701x over previous
//
#include <hip/hip_runtime.h>

#define VOCAB 100000
#define DIM 128
#define BATCH 65536
#define NEG 5

#define TPB 256
#define GRPS 16                       // 16-lane groups per block
#define BLOCKS (BATCH / (GRPS * 2))   // 2048: each group pipelines 2 elements

__device__ __forceinline__ float log_sigmoid(float x) {
    return fminf(x, 0.0f) - log1pf(expf(-fabsf(x)));
}
__device__ __forceinline__ float dot4(float4 a, float4 b) {
    return a.x * b.x + a.y * b.y + a.z * b.z + a.w * b.w;
}

__global__ __launch_bounds__(TPB, 2) void g2v_partial(
    const float* __restrict__ W_in, const float* __restrict__ W_ctx,
    const int* __restrict__ input_word, const int* __restrict__ context_word,
    const int* __restrict__ neg_idx, float* __restrict__ block_sums)
{
    const int lane16 = threadIdx.x & 15;
    const int grp = threadIdx.x >> 4;
    const int b0 = blockIdx.x * GRPS + grp;          // element 0
    const int b1 = b0 + BLOCKS * GRPS;               // element 1

    const float4* __restrict__ W_in4 = (const float4*)W_in;
    const float4* __restrict__ W_ctx4 = (const float4*)W_ctx;

    // ---- all index loads first ----
    const int iw0 = input_word[b0];
    const int cw0 = context_word[b0];
    const int iw1 = input_word[b1];
    const int cw1 = context_word[b1];
    int nw0[NEG], nw1[NEG];
    #pragma unroll
    for (int k = 0; k < NEG; ++k) nw0[k] = neg_idx[b0 * NEG + k];
    #pragma unroll
    for (int k = 0; k < NEG; ++k) nw1[k] = neg_idx[b1 * NEG + k];

    // ---- issue ALL 28 row loads before any compute (deep MLP) ----
    const float4* ri0 = W_in4 + iw0 * 32 + lane16;
    const float4 a0_0 = ri0[0], a0_1 = ri0[16];
    const float4* rc0 = W_ctx4 + cw0 * 32 + lane16;
    const float4 c0_0 = rc0[0], c0_1 = rc0[16];
    float4 e0_lo[NEG], e0_hi[NEG];
    #pragma unroll
    for (int k = 0; k < NEG; ++k) {
        const float4* rn = W_in4 + nw0[k] * 32 + lane16;
        e0_lo[k] = rn[0];
        e0_hi[k] = rn[16];
    }

    const float4* ri1 = W_in4 + iw1 * 32 + lane16;
    const float4 a1_0 = ri1[0], a1_1 = ri1[16];
    const float4* rc1 = W_ctx4 + cw1 * 32 + lane16;
    const float4 c1_0 = rc1[0], c1_1 = rc1[16];
    float4 e1_lo[NEG], e1_hi[NEG];
    #pragma unroll
    for (int k = 0; k < NEG; ++k) {
        const float4* rn = W_in4 + nw1[k] * 32 + lane16;
        e1_lo[k] = rn[0];
        e1_hi[k] = rn[16];
    }

    // ---- compute element 0 (element 1 loads still in flight) ----
    float pos0 = dot4(a0_0, c0_0) + dot4(a0_1, c0_1);
    float nd0[NEG];
    #pragma unroll
    for (int k = 0; k < NEG; ++k)
        nd0[k] = dot4(e0_lo[k], a0_0) + dot4(e0_hi[k], a0_1);

    #pragma unroll
    for (int m = 1; m <= 8; m <<= 1) {
        pos0 += __shfl_xor(pos0, m);
        #pragma unroll
        for (int k = 0; k < NEG; ++k) nd0[k] += __shfl_xor(nd0[k], m);
    }

    // ---- compute element 1 ----
    float pos1 = dot4(a1_0, c1_0) + dot4(a1_1, c1_1);
    float nd1[NEG];
    #pragma unroll
    for (int k = 0; k < NEG; ++k)
        nd1[k] = dot4(e1_lo[k], a1_0) + dot4(e1_hi[k], a1_1);

    #pragma unroll
    for (int m = 1; m <= 8; m <<= 1) {
        pos1 += __shfl_xor(pos1, m);
        #pragma unroll
        for (int k = 0; k < NEG; ++k) nd1[k] += __shfl_xor(nd1[k], m);
    }

    float loss = 0.0f;
    if (lane16 == 0) {
        loss = log_sigmoid(pos0) + log_sigmoid(pos1);
        #pragma unroll
        for (int k = 0; k < NEG; ++k)
            loss += log_sigmoid(-nd0[k]) + log_sigmoid(-nd1[k]);
    }

    __shared__ float s[GRPS];
    if (lane16 == 0) s[grp] = loss;
    __syncthreads();
    if (threadIdx.x == 0) {
        float t = 0.0f;
        #pragma unroll
        for (int i = 0; i < GRPS; ++i) t += s[i];
        block_sums[blockIdx.x] = t;
    }
}

__global__ __launch_bounds__(1024) void g2v_final(
    const float* __restrict__ block_sums, int n, float* __restrict__ out)
{
    __shared__ float s[1024];
    float t = 0.0f;
    for (int i = threadIdx.x; i < n; i += 1024) t += block_sums[i];
    s[threadIdx.x] = t;
    __syncthreads();
    for (int w = 512; w > 0; w >>= 1) {
        if (threadIdx.x < w) s[threadIdx.x] += s[threadIdx.x + w];
        __syncthreads();
    }
    if (threadIdx.x == 0) out[0] = -s[0] / (float)BATCH;
}

extern "C" void kernel_launch(void* const* d_in, const int* in_sizes, int n_in,
                              void* d_out, int out_size, void* d_ws, size_t ws_size,
                              hipStream_t stream) {
    const float* W_in        = (const float*)d_in[0];
    const float* W_ctx       = (const float*)d_in[1];
    const int*   input_word  = (const int*)d_in[2];
    const int*   context_word= (const int*)d_in[3];
    const int*   neg_idx     = (const int*)d_in[4];

    float* block_sums = (float*)d_ws;   // BLOCKS floats
    float* out        = (float*)d_out;

    g2v_partial<<<BLOCKS, TPB, 0, stream>>>(W_in, W_ctx, input_word,
                                            context_word, neg_idx, block_sums);
    g2v_final<<<1, 1024, 0, stream>>>(block_sums, BLOCKS, out);
}